// Round 5
// baseline (721.070 us; speedup 1.0000x reference)
//
#include <hip/hip_runtime.h>

constexpr int kN = 100000;
constexpr int kNpad = 100096;      // 782 * 128
constexpr int kE = 800000;
constexpr int kB = 128;
constexpr int kBinsPerDir = 391;   // ceil(100000/256)
constexpr int kNB = 782;           // 2 * 391
constexpr float kInvBN = 0.99999500003749968f; // 1/sqrt(1+1e-5)

typedef short s16x8 __attribute__((ext_vector_type(8)));
typedef float f32x4 __attribute__((ext_vector_type(4)));

__device__ inline ushort bf16rne(float f) {
  uint u = __builtin_bit_cast(uint, f);
  u += 0x7fffu + ((u >> 16) & 1u);
  return (ushort)(u >> 16);
}
__device__ inline float bflo(uint v) { return __builtin_bit_cast(float, v << 16); }
__device__ inline float bfhi(uint v) { return __builtin_bit_cast(float, v & 0xffff0000u); }

// ---------------- CSR build: two-level counting sort ----------------
// bin = dir*391 + (dst>>8); payload = src | (dst&255)<<17  (src < 2^17)

__global__ __launch_bounds__(256) void bincount_kernel(const int* __restrict__ ei,
                                                       const int* __restrict__ ed,
                                                       int* __restrict__ bincnt) {
  int e = blockIdx.x * 256 + threadIdx.x;
  if (e >= kE) return;
  int bin = ed[e] * kBinsPerDir + (ei[kE + e] >> 8);
  atomicAdd(&bincnt[bin], 1);
}

__global__ __launch_bounds__(256) void binscan_kernel(const int* __restrict__ bincnt,
                                                      int* __restrict__ binoff) {
  __shared__ int s[256];
  int t = threadIdx.x;
  int base = t * 4;
  int v0 = (base + 0 < kNB) ? bincnt[base + 0] : 0;
  int v1 = (base + 1 < kNB) ? bincnt[base + 1] : 0;
  int v2 = (base + 2 < kNB) ? bincnt[base + 2] : 0;
  int v3 = (base + 3 < kNB) ? bincnt[base + 3] : 0;
  int tsum = v0 + v1 + v2 + v3;
  s[t] = tsum;
  __syncthreads();
  for (int d = 1; d < 256; d <<= 1) {
    int tmp = (t >= d) ? s[t - d] : 0;
    __syncthreads();
    s[t] += tmp;
    __syncthreads();
  }
  int excl = s[t] - tsum;
  if (base + 0 <= kNB) binoff[base + 0] = excl;
  excl += v0;
  if (base + 1 <= kNB) binoff[base + 1] = excl;
  excl += v1;
  if (base + 2 <= kNB) binoff[base + 2] = excl;
  excl += v2;
  if (base + 3 <= kNB) binoff[base + 3] = excl;
}

__global__ __launch_bounds__(256) void binscatter_kernel(const int* __restrict__ ei,
                                                         const int* __restrict__ ed,
                                                         const int* __restrict__ binoff,
                                                         int* __restrict__ bincur,
                                                         uint* __restrict__ binbuf) {
  int e = blockIdx.x * 256 + threadIdx.x;
  if (e >= kE) return;
  int dst = ei[kE + e];
  int bin = ed[e] * kBinsPerDir + (dst >> 8);
  int pos = atomicAdd(&bincur[bin], 1);
  binbuf[binoff[bin] + pos] = (uint)ei[e] | ((uint)(dst & 255) << 17);
}

// one block per bin: local degree count + scan, dense csr/cnt/off writes
__global__ __launch_bounds__(256) void binfill_kernel(const uint* __restrict__ binbuf,
                                                      const int* __restrict__ binoff,
                                                      int* __restrict__ csr,
                                                      int* __restrict__ cnt,
                                                      int* __restrict__ off) {
  __shared__ int lcnt[256];
  __shared__ int ls[256];
  __shared__ int lpos[256];
  int b = blockIdx.x;
  int t = threadIdx.x;
  int dir = (b >= kBinsPerDir) ? 1 : 0;
  int nodeBase = (b - dir * kBinsPerDir) << 8;
  int e0 = binoff[b], e1 = binoff[b + 1];
  lcnt[t] = 0;
  __syncthreads();
  for (int e = e0 + t; e < e1; e += 256) atomicAdd(&lcnt[binbuf[e] >> 17], 1);
  __syncthreads();
  int my = lcnt[t];
  ls[t] = my;
  __syncthreads();
  for (int d = 1; d < 256; d <<= 1) {
    int tmp = (t >= d) ? ls[t - d] : 0;
    __syncthreads();
    ls[t] += tmp;
    __syncthreads();
  }
  int excl = ls[t] - my;
  lpos[t] = e0 + excl;
  int node = nodeBase + t;
  if (node < kN) {
    int g = dir * kN + node;
    cnt[g] = my;
    off[g] = e0 + excl;
  }
  __syncthreads();
  for (int e = e0 + t; e < e1; e += 256) {
    uint v = binbuf[e];
    int pos = atomicAdd(&lpos[v >> 17], 1);
    csr[pos] = (int)(v & 0x1FFFFu);
  }
}

// graph start offsets from sorted batch
__global__ __launch_bounds__(256) void gstart_kernel(const int* __restrict__ batch,
                                                     int* __restrict__ gstart) {
  int n = blockIdx.x * 256 + threadIdx.x;
  if (n >= kN) return;
  int b = batch[n];
  int bprev = (n == 0) ? -1 : batch[n - 1];
  for (int g = bprev + 1; g <= b; ++g) gstart[g] = n;
  if (n == kN - 1)
    for (int g = b + 1; g <= kB; ++g) gstart[g] = kN;
}

// ---------------- precompute: x -> bf16 (padded), weights -> packed bf16 ----------------

__global__ __launch_bounds__(256) void xconv_kernel(const float* __restrict__ x,
                                                    ushort* __restrict__ xb) {
  int gid = blockIdx.x * 256 + threadIdx.x;
  int i4 = gid * 4;
  if (i4 >= kNpad * 128) return;
  ushort4 r;
  if (i4 < kN * 128) {
    float4 v = *(const float4*)&x[i4];
    r.x = bf16rne(v.x); r.y = bf16rne(v.y); r.z = bf16rne(v.z); r.w = bf16rne(v.w);
  } else {
    r.x = r.y = r.z = r.w = 0;
  }
  *(ushort4*)&xb[i4] = r;
}

struct WPtrs { const float* Wl[6]; const float* Wr[6]; };

__global__ __launch_bounds__(256) void wprep_kernel(WPtrs p, ushort* __restrict__ Wb) {
  int id = blockIdx.x * 256 + threadIdx.x; // L*32768 + o*256 + k
  int L = id >> 15;
  int o = (id >> 8) & 127, k = id & 255;
  const float* src = (k < 128) ? p.Wl[L] : p.Wr[L];
  Wb[id] = bf16rne(src[o * 128 + (k & 127)]);
}

// ---------------- Aggregation: 8-lane group per node, unroll x2 ----------------

__global__ __launch_bounds__(256) void agg_kernel(const ushort* __restrict__ h,
                                                  ushort* __restrict__ aggout,
                                                  const int* __restrict__ off,
                                                  const int* __restrict__ cnt,
                                                  const int* __restrict__ csr,
                                                  int dirbase) {
  int gid = blockIdx.x * 256 + threadIdx.x;
  int node = gid >> 3;
  int lane = gid & 7;
  if (node >= kN) return;
  int bkt = dirbase + node;
  int s = off[bkt];
  int c = cnt[bkt];
  float acc[16];
#pragma unroll
  for (int i = 0; i < 16; ++i) acc[i] = 0.f;
  const ushort* hp = h + lane * 16;
  int e = 0;
  for (; e + 2 <= c; e += 2) {
    int s0 = csr[s + e];
    int s1 = csr[s + e + 1];
    const ushort* p0 = hp + (size_t)s0 * 128;
    const ushort* p1 = hp + (size_t)s1 * 128;
    uint4 a0 = *(const uint4*)p0;
    uint4 a1 = *(const uint4*)(p0 + 8);
    uint4 b0 = *(const uint4*)p1;
    uint4 b1 = *(const uint4*)(p1 + 8);
    acc[0] += bflo(a0.x) + bflo(b0.x); acc[1] += bfhi(a0.x) + bfhi(b0.x);
    acc[2] += bflo(a0.y) + bflo(b0.y); acc[3] += bfhi(a0.y) + bfhi(b0.y);
    acc[4] += bflo(a0.z) + bflo(b0.z); acc[5] += bfhi(a0.z) + bfhi(b0.z);
    acc[6] += bflo(a0.w) + bflo(b0.w); acc[7] += bfhi(a0.w) + bfhi(b0.w);
    acc[8] += bflo(a1.x) + bflo(b1.x); acc[9] += bfhi(a1.x) + bfhi(b1.x);
    acc[10] += bflo(a1.y) + bflo(b1.y); acc[11] += bfhi(a1.y) + bfhi(b1.y);
    acc[12] += bflo(a1.z) + bflo(b1.z); acc[13] += bfhi(a1.z) + bfhi(b1.z);
    acc[14] += bflo(a1.w) + bflo(b1.w); acc[15] += bfhi(a1.w) + bfhi(b1.w);
  }
  if (e < c) {
    int s0 = csr[s + e];
    const ushort* p0 = hp + (size_t)s0 * 128;
    uint4 a0 = *(const uint4*)p0;
    uint4 a1 = *(const uint4*)(p0 + 8);
    acc[0] += bflo(a0.x); acc[1] += bfhi(a0.x);
    acc[2] += bflo(a0.y); acc[3] += bfhi(a0.y);
    acc[4] += bflo(a0.z); acc[5] += bfhi(a0.z);
    acc[6] += bflo(a0.w); acc[7] += bfhi(a0.w);
    acc[8] += bflo(a1.x); acc[9] += bfhi(a1.x);
    acc[10] += bflo(a1.y); acc[11] += bfhi(a1.y);
    acc[12] += bflo(a1.z); acc[13] += bfhi(a1.z);
    acc[14] += bflo(a1.w); acc[15] += bfhi(a1.w);
  }
  float iv = 1.0f / fmaxf((float)c, 1.0f);
  uint4 r0, r1;
  r0.x = (uint)bf16rne(acc[0] * iv) | ((uint)bf16rne(acc[1] * iv) << 16);
  r0.y = (uint)bf16rne(acc[2] * iv) | ((uint)bf16rne(acc[3] * iv) << 16);
  r0.z = (uint)bf16rne(acc[4] * iv) | ((uint)bf16rne(acc[5] * iv) << 16);
  r0.w = (uint)bf16rne(acc[6] * iv) | ((uint)bf16rne(acc[7] * iv) << 16);
  r1.x = (uint)bf16rne(acc[8] * iv) | ((uint)bf16rne(acc[9] * iv) << 16);
  r1.y = (uint)bf16rne(acc[10] * iv) | ((uint)bf16rne(acc[11] * iv) << 16);
  r1.z = (uint)bf16rne(acc[12] * iv) | ((uint)bf16rne(acc[13] * iv) << 16);
  r1.w = (uint)bf16rne(acc[14] * iv) | ((uint)bf16rne(acc[15] * iv) << 16);
  ushort* op = aggout + (size_t)node * 128 + lane * 16;
  *(uint4*)op = r0;
  *(uint4*)(op + 8) = r1;
}

// ---------------- MFMA layer (unchanged, verified) ----------------

__global__ __launch_bounds__(256) void layer_mfma_kernel(
    ushort* __restrict__ mean_io, const ushort* __restrict__ h,
    const ushort* __restrict__ Wb, const float* __restrict__ bl) {
  __shared__ ushort Wlds[128 * 256];

  const int t = threadIdx.x;
#pragma unroll
  for (int it = 0; it < 16; ++it) {
    int u = t + 256 * it;
    int o = u >> 5, b = u & 31;
    uint4 v = *(const uint4*)(Wb + (size_t)u * 8);
    *(uint4*)((char*)Wlds + o * 512 + ((b ^ (o & 7)) << 4)) = v;
  }
  __syncthreads();

  const int w = t >> 6;
  const int l = t & 63;
  const int lr = l & 15;
  const int lq = l >> 4;
  const int nodebase = blockIdx.x * 128 + w * 32;
  const int swz = lr & 7;

  f32x4 acc[2][8];
#pragma unroll
  for (int i = 0; i < 2; ++i)
#pragma unroll
    for (int j = 0; j < 8; ++j) acc[i][j] = {0.f, 0.f, 0.f, 0.f};

#pragma unroll 2
  for (int kk = 0; kk < 8; ++kk) {
    const ushort* src = (kk < 4) ? mean_io : h;
    const int kb = (kk & 3) * 32 + lq * 8;
    s16x8 a0 = *(const s16x8*)(src + (size_t)(nodebase + lr) * 128 + kb);
    s16x8 a1 = *(const s16x8*)(src + (size_t)(nodebase + 16 + lr) * 128 + kb);
    const int ks = (kk * 4 + lq) ^ swz;
#pragma unroll
    for (int j = 0; j < 8; ++j) {
      int o = j * 16 + lr;
      s16x8 wf = *(const s16x8*)((const char*)Wlds + o * 512 + (ks << 4));
      acc[0][j] = __builtin_amdgcn_mfma_f32_16x16x32_bf16(wf, a0, acc[0][j], 0, 0, 0);
      acc[1][j] = __builtin_amdgcn_mfma_f32_16x16x32_bf16(wf, a1, acc[1][j], 0, 0, 0);
    }
  }

#pragma unroll
  for (int i = 0; i < 2; ++i) {
    int node = nodebase + i * 16 + lr;
    if (node < kN) {
#pragma unroll
      for (int j = 0; j < 8; ++j) {
        int o = j * 16 + lq * 4;
        float4 bv = *(const float4*)(bl + o);
        ushort4 r;
        r.x = bf16rne(fmaxf(acc[i][j][0] + bv.x, 0.f));
        r.y = bf16rne(fmaxf(acc[i][j][1] + bv.y, 0.f));
        r.z = bf16rne(fmaxf(acc[i][j][2] + bv.z, 0.f));
        r.w = bf16rne(fmaxf(acc[i][j][3] + bv.w, 0.f));
        *(ushort4*)(mean_io + (size_t)node * 128 + o) = r;
      }
    }
  }
}

// ---------------- Pooling: 16 chunks per graph ----------------

__global__ __launch_bounds__(256) void pool_kernel(const ushort* __restrict__ h,
                                                   const int* __restrict__ gstart,
                                                   float* __restrict__ comb_raw,
                                                   int base) {
  __shared__ float part[4 * 128];
  int gb = blockIdx.x;
  int graph = gb >> 4;
  int chunk = gb & 15;
  int t = threadIdx.x;
  int slice = t >> 6;
  int col = t & 63;
  int s = gstart[graph];
  int e = gstart[graph + 1];
  int len = e - s;
  int c0 = s + (int)((long long)len * chunk / 16);
  int c1 = s + (int)((long long)len * (chunk + 1) / 16);
  float ax = 0.f, ay = 0.f;
  for (int n = c0 + slice; n < c1; n += 4) {
    uint v = *(const uint*)(h + (size_t)n * 128 + col * 2);
    ax += bflo(v);
    ay += bfhi(v);
  }
  part[slice * 128 + col * 2] = ax;
  part[slice * 128 + col * 2 + 1] = ay;
  __syncthreads();
  if (t < 128) {
    float v = part[t] + part[128 + t] + part[256 + t] + part[384 + t];
    atomicAdd(&comb_raw[graph * 256 + base + t], v);
  }
}

// ---------------- Heads ----------------

__global__ __launch_bounds__(256) void head_kernel(
    const float* __restrict__ comb_raw, const int* __restrict__ gstart,
    const float* __restrict__ gf,
    const float* __restrict__ neg, const float* __restrict__ neb,
    const float* __restrict__ fc1W, const float* __restrict__ fc1b,
    const float* __restrict__ bn1g, const float* __restrict__ bn1b,
    const float* __restrict__ fc2W, const float* __restrict__ fc2b,
    const float* __restrict__ fc3aW, const float* __restrict__ fc3ab,
    const float* __restrict__ fc3bW, const float* __restrict__ fc3bb,
    const float* __restrict__ ncg, const float* __restrict__ ncb,
    float* __restrict__ out) {
  __shared__ float wlds[6979];
  __shared__ float comb[256];
  __shared__ float x3[261];
  __shared__ float r2s[2];

  const int b = blockIdx.x;
  const int t = threadIdx.x;

  for (int i = t; i < 4112; i += 256) wlds[i] = fc1W[i];
  for (int i = t; i < 518; i += 256) wlds[4112 + i] = fc2W[i];
  for (int i = t; i < 1044; i += 256) wlds[4630 + i] = fc3aW[i];
  for (int i = t; i < 1305; i += 256) wlds[5674 + i] = fc3bW[i];

  float cntf = fmaxf((float)(gstart[b + 1] - gstart[b]), 1.0f);
  if (t < 256) comb[t] = neg[t] * ((comb_raw[b * 256 + t] / cntf) * kInvBN) + neb[t];
  __syncthreads();

  float g1 = gf[b * 5 + 1], g2 = gf[b * 5 + 2], g3 = gf[b * 5 + 3], g4 = gf[b * 5 + 4];
  const int g = t >> 3, l8 = t & 7;

  {
    float p = 0.f;
    if (g < 16) {
      const float* w = &wlds[g * 257];
      for (int j = l8; j < 256; j += 8) p += comb[j] * w[j];
    } else if (g < 18) {
      const float* w = &wlds[4112 + (g - 16) * 259];
      for (int j = l8; j < 256; j += 8) p += comb[j] * w[j];
    }
    p += __shfl_xor(p, 1);
    p += __shfl_xor(p, 2);
    p += __shfl_xor(p, 4);
    if (l8 == 0) {
      if (g < 16) {
        float z = fmaxf(p + wlds[g * 257 + 256] * g4 + fc1b[g], 0.f);
        out[b * 16 + g] = bn1g[g] * (z * kInvBN) + bn1b[g];
      } else if (g < 18) {
        int o = g - 16;
        const float* w = &wlds[4112 + o * 259];
        float z = fmaxf(p + w[256] * g2 + w[257] * g3 + w[258] * g4 + fc2b[o], 0.f);
        out[2048 + b * 2 + o] = z;
        r2s[o] = z;
      }
    }
  }
  for (int j = t; j < 261; j += 256) {
    float v;
    if (j < 256) v = comb[j];
    else if (j == 256) v = g2;
    else if (j == 257) v = g1;
    else if (j == 258) v = g2;
    else if (j == 259) v = g3;
    else v = g4;
    x3[j] = ncg[j] * (v * kInvBN) + ncb[j];
  }
  __syncthreads();
  int pred = (r2s[1] > r2s[0]) ? 1 : 0;

  {
    float p = 0.f;
    if (g < 4) {
      const float* w = &wlds[4630 + g * 261];
      for (int j = l8; j < 261; j += 8) p += x3[j] * w[j];
    } else if (g < 9) {
      const float* w = &wlds[5674 + (g - 4) * 261];
      for (int j = l8; j < 261; j += 8) p += x3[j] * w[j];
    }
    p += __shfl_xor(p, 1);
    p += __shfl_xor(p, 2);
    p += __shfl_xor(p, 4);
    if (l8 == 0) {
      if (g < 4) {
        float v = p + fc3ab[g];
        out[2304 + b * 9 + g] = (pred == 0) ? v : 0.f;
      } else if (g < 9) {
        int o = g - 4;
        float v = p + fc3bb[o];
        out[2304 + b * 9 + 4 + o] = (pred == 1) ? v : 0.f;
      }
    }
  }
}

// ---------------- Launch ----------------

extern "C" void kernel_launch(void* const* d_in, const int* in_sizes, int n_in,
                              void* d_out, int out_size, void* d_ws, size_t ws_size,
                              hipStream_t stream) {
  (void)in_sizes; (void)n_in; (void)out_size; (void)ws_size;
  const float* x   = (const float*)d_in[0];
  const int* ei    = (const int*)d_in[1];
  const int* ed    = (const int*)d_in[2];
  const int* batch = (const int*)d_in[3];
  const float* gf  = (const float*)d_in[4];

  char* ws = (char*)d_ws;
  auto carve = [&](size_t bytes) -> void* {
    void* p = ws;
    ws += (bytes + 255) & ~(size_t)255;
    return p;
  };
  int* cnt        = (int*)carve(2 * kN * sizeof(int));
  int* off        = (int*)carve(2 * kN * sizeof(int));
  int* bincnt     = (int*)carve(kNB * sizeof(int));
  int* bincur     = (int*)carve(kNB * sizeof(int));
  int* binoff     = (int*)carve((kNB + 1) * sizeof(int));
  uint* binbuf    = (uint*)carve(kE * sizeof(uint));
  int* gstart     = (int*)carve((kB + 1) * sizeof(int));
  int* csr        = (int*)carve(kE * sizeof(int));
  float* comb_raw = (float*)carve(kB * 256 * sizeof(float));
  ushort* xb      = (ushort*)carve((size_t)kNpad * 128 * 2);
  ushort* buf0    = (ushort*)carve((size_t)kNpad * 128 * 2);
  ushort* buf1    = (ushort*)carve((size_t)kNpad * 128 * 2);
  ushort* Wb      = (ushort*)carve(6 * 128 * 256 * 2);

  hipMemsetAsync(bincnt, 0, kNB * sizeof(int), stream);
  hipMemsetAsync(bincur, 0, kNB * sizeof(int), stream);
  hipMemsetAsync(comb_raw, 0, kB * 256 * sizeof(float), stream);

  xconv_kernel<<<(kNpad * 128 / 4 + 255) / 256, 256, 0, stream>>>(x, xb);
  WPtrs wp;
  for (int L = 0; L < 6; ++L) {
    wp.Wl[L] = (const float*)d_in[6 + 3 * L];
    wp.Wr[L] = (const float*)d_in[6 + 3 * L + 2];
  }
  wprep_kernel<<<768, 256, 0, stream>>>(wp, Wb);

  bincount_kernel<<<(kE + 255) / 256, 256, 0, stream>>>(ei, ed, bincnt);
  binscan_kernel<<<1, 256, 0, stream>>>(bincnt, binoff);
  binscatter_kernel<<<(kE + 255) / 256, 256, 0, stream>>>(ei, ed, binoff, bincur, binbuf);
  binfill_kernel<<<kNB, 256, 0, stream>>>(binbuf, binoff, csr, cnt, off);
  gstart_kernel<<<(kN + 255) / 256, 256, 0, stream>>>(batch, gstart);

  auto aggL = [&](const ushort* h, ushort* a, int dirbase) {
    agg_kernel<<<kN * 8 / 256 + 1, 256, 0, stream>>>(h, a, off, cnt, csr, dirbase);
  };
  auto layerL = [&](ushort* a, const ushort* h, int L) {
    layer_mfma_kernel<<<kNpad / 128, 256, 0, stream>>>(
        a, h, Wb + (size_t)L * 32768, (const float*)d_in[6 + 3 * L + 1]);
  };

  // pre chain (dir bucket base 0)
  aggL(xb, buf0, 0);     layerL(buf0, xb, 0);
  aggL(buf0, buf1, 0);   layerL(buf1, buf0, 1);
  aggL(buf1, buf0, 0);   layerL(buf0, buf1, 2);
  pool_kernel<<<kB * 16, 256, 0, stream>>>(buf0, gstart, comb_raw, 0);

  // suc chain (dir bucket base kN)
  aggL(xb, buf1, kN);    layerL(buf1, xb, 3);
  aggL(buf1, buf0, kN);  layerL(buf0, buf1, 4);
  aggL(buf0, buf1, kN);  layerL(buf1, buf0, 5);
  pool_kernel<<<kB * 16, 256, 0, stream>>>(buf1, gstart, comb_raw, 128);

  head_kernel<<<kB, 256, 0, stream>>>(
      comb_raw, gstart, gf,
      (const float*)d_in[24], (const float*)d_in[25],
      (const float*)d_in[26], (const float*)d_in[27],
      (const float*)d_in[28], (const float*)d_in[29],
      (const float*)d_in[30], (const float*)d_in[31],
      (const float*)d_in[32], (const float*)d_in[33],
      (const float*)d_in[34], (const float*)d_in[35],
      (const float*)d_in[36], (const float*)d_in[37],
      (float*)d_out);
}

// Round 6
// 411.229 us; speedup vs baseline: 1.7535x; 1.7535x over previous
//
#include <hip/hip_runtime.h>

constexpr int kN = 100000;
constexpr int kNpad = 100096;      // 1564 * 64
constexpr int kE = 800000;
constexpr int kB = 128;
constexpr float kInvBN = 0.99999500003749968f; // 1/sqrt(1+1e-5)

typedef short s16x8 __attribute__((ext_vector_type(8)));
typedef float f32x4 __attribute__((ext_vector_type(4)));

__device__ inline ushort bf16rne(float f) {
  uint u = __builtin_bit_cast(uint, f);
  u += 0x7fffu + ((u >> 16) & 1u);
  return (ushort)(u >> 16);
}
__device__ inline float bflo(uint v) { return __builtin_bit_cast(float, v << 16); }
__device__ inline float bfhi(uint v) { return __builtin_bit_cast(float, v & 0xffff0000u); }
__device__ inline uint pack2(float a, float b) {
  return (uint)bf16rne(a) | ((uint)bf16rne(b) << 16);
}

// ---------------- CSR build (round-4 scheme: 200k buckets, low contention) ----------------

__global__ __launch_bounds__(256) void count_kernel(const int* __restrict__ ei,
                                                    const int* __restrict__ ed,
                                                    int* __restrict__ cnt) {
  int e = blockIdx.x * 256 + threadIdx.x;
  if (e >= kE) return;
  atomicAdd(&cnt[ed[e] * kN + ei[kE + e]], 1);
}

__global__ __launch_bounds__(256) void scan1_kernel(const int* __restrict__ in,
                                                    int* __restrict__ out,
                                                    int* __restrict__ bsum, int M) {
  __shared__ int s[256];
  int t = threadIdx.x;
  int idx = blockIdx.x * 1024 + t * 4;
  int4 v = {0, 0, 0, 0};
  if (idx < M) v = *(const int4*)&in[idx];
  int tsum = v.x + v.y + v.z + v.w;
  s[t] = tsum;
  __syncthreads();
  for (int d = 1; d < 256; d <<= 1) {
    int tmp = (t >= d) ? s[t - d] : 0;
    __syncthreads();
    s[t] += tmp;
    __syncthreads();
  }
  int excl = s[t] - tsum;
  if (idx < M) {
    int4 o;
    o.x = excl; o.y = excl + v.x; o.z = o.y + v.y; o.w = o.z + v.z;
    *(int4*)&out[idx] = o;
  }
  if (t == 255) bsum[blockIdx.x] = s[255];
}

__global__ __launch_bounds__(256) void scan2_kernel(int* __restrict__ bsum, int nb) {
  __shared__ int s[256];
  int t = threadIdx.x;
  int v = (t < nb) ? bsum[t] : 0;
  s[t] = v;
  __syncthreads();
  for (int d = 1; d < 256; d <<= 1) {
    int tmp = (t >= d) ? s[t - d] : 0;
    __syncthreads();
    s[t] += tmp;
    __syncthreads();
  }
  if (t < nb) bsum[t] = s[t] - v;
}

__global__ __launch_bounds__(256) void scan3_kernel(int* __restrict__ out,
                                                    const int* __restrict__ bsum, int M) {
  int idx = blockIdx.x * 1024 + threadIdx.x * 4;
  int add = bsum[blockIdx.x];
  if (idx < M) {
    int4 o = *(int4*)&out[idx];
    o.x += add; o.y += add; o.z += add; o.w += add;
    *(int4*)&out[idx] = o;
  }
}

__global__ __launch_bounds__(256) void fill_kernel(const int* __restrict__ ei,
                                                   const int* __restrict__ ed,
                                                   const int* __restrict__ off,
                                                   int* __restrict__ cursor,
                                                   int* __restrict__ csr) {
  int e = blockIdx.x * 256 + threadIdx.x;
  if (e >= kE) return;
  int bkt = ed[e] * kN + ei[kE + e];
  int pos = atomicAdd(&cursor[bkt], 1);
  csr[off[bkt] + pos] = ei[e];
}

// graph start offsets from sorted batch
__global__ __launch_bounds__(256) void gstart_kernel(const int* __restrict__ batch,
                                                     int* __restrict__ gstart) {
  int n = blockIdx.x * 256 + threadIdx.x;
  if (n >= kN) return;
  int b = batch[n];
  int bprev = (n == 0) ? -1 : batch[n - 1];
  for (int g = bprev + 1; g <= b; ++g) gstart[g] = n;
  if (n == kN - 1)
    for (int g = b + 1; g <= kB; ++g) gstart[g] = kN;
}

// ---------------- precompute: x -> bf16 (padded), weights -> packed bf16 ----------------

__global__ __launch_bounds__(256) void xconv_kernel(const float* __restrict__ x,
                                                    ushort* __restrict__ xb) {
  int gid = blockIdx.x * 256 + threadIdx.x;
  int i4 = gid * 4;
  if (i4 >= kNpad * 128) return;
  ushort4 r;
  if (i4 < kN * 128) {
    float4 v = *(const float4*)&x[i4];
    r.x = bf16rne(v.x); r.y = bf16rne(v.y); r.z = bf16rne(v.z); r.w = bf16rne(v.w);
  } else {
    r.x = r.y = r.z = r.w = 0;
  }
  *(ushort4*)&xb[i4] = r;
}

struct WPtrs { const float* Wl[6]; const float* Wr[6]; };

__global__ __launch_bounds__(256) void wprep_kernel(WPtrs p, ushort* __restrict__ Wb) {
  int id = blockIdx.x * 256 + threadIdx.x; // L*32768 + o*256 + k
  int L = id >> 15;
  int o = (id >> 8) & 127, k = id & 255;
  const float* src = (k < 128) ? p.Wl[L] : p.Wr[L];
  Wb[id] = bf16rne(src[o * 128 + (k & 127)]);
}

// ---------------- Fused SAGE layer: gather-mean in registers + MFMA ----------------
// out = relu([mean|h] @ W^T + b). Wave computes a 16-node x 128-out tile.
// Lane (lr,lq) gathers exactly the mean channels it feeds to MFMA:
// node = base + lr, channels q*32 + lq*8 .. +7 for q=0..3 (4x16B per edge row).

__global__ __launch_bounds__(256) void fused_layer_kernel(
    const ushort* __restrict__ h,      // [kNpad][128] bf16 input features
    ushort* __restrict__ outp,         // [kNpad][128] bf16 output
    const ushort* __restrict__ Wb,     // [128][256] bf16
    const float* __restrict__ bl,
    const int* __restrict__ off,
    const int* __restrict__ cnt,
    const int* __restrict__ csr,
    int dirbase) {
  __shared__ ushort Wlds[128 * 256];   // 64 KB, 16B-block XOR swizzled

  const int t = threadIdx.x;
#pragma unroll
  for (int it = 0; it < 16; ++it) {
    int u = t + 256 * it;
    int o = u >> 5, b = u & 31;
    uint4 v = *(const uint4*)(Wb + (size_t)u * 8);
    *(uint4*)((char*)Wlds + o * 512 + ((b ^ (o & 7)) << 4)) = v;
  }

  const int w = t >> 6;
  const int l = t & 63;
  const int lr = l & 15;
  const int lq = l >> 4;
  const int node = blockIdx.x * 64 + w * 16 + lr;
  const int swz = lr & 7;

  // ---- gather + mean (registers only) ----
  float ga[32];
#pragma unroll
  for (int i = 0; i < 32; ++i) ga[i] = 0.f;
  int c = 0;
  if (node < kN) {
    int bkt = dirbase + node;
    int s = off[bkt];
    c = cnt[bkt];
    const ushort* hp = h + lq * 8;
    int e = 0;
    for (; e + 2 <= c; e += 2) {
      int s0 = csr[s + e];
      int s1 = csr[s + e + 1];
      const ushort* p0 = hp + (size_t)s0 * 128;
      const ushort* p1 = hp + (size_t)s1 * 128;
      uint4 va[4], vb[4];
#pragma unroll
      for (int q = 0; q < 4; ++q) va[q] = *(const uint4*)(p0 + q * 32);
#pragma unroll
      for (int q = 0; q < 4; ++q) vb[q] = *(const uint4*)(p1 + q * 32);
#pragma unroll
      for (int q = 0; q < 4; ++q) {
        ga[q * 8 + 0] += bflo(va[q].x) + bflo(vb[q].x);
        ga[q * 8 + 1] += bfhi(va[q].x) + bfhi(vb[q].x);
        ga[q * 8 + 2] += bflo(va[q].y) + bflo(vb[q].y);
        ga[q * 8 + 3] += bfhi(va[q].y) + bfhi(vb[q].y);
        ga[q * 8 + 4] += bflo(va[q].z) + bflo(vb[q].z);
        ga[q * 8 + 5] += bfhi(va[q].z) + bfhi(vb[q].z);
        ga[q * 8 + 6] += bflo(va[q].w) + bflo(vb[q].w);
        ga[q * 8 + 7] += bfhi(va[q].w) + bfhi(vb[q].w);
      }
    }
    if (e < c) {
      int s0 = csr[s + e];
      const ushort* p0 = hp + (size_t)s0 * 128;
      uint4 va[4];
#pragma unroll
      for (int q = 0; q < 4; ++q) va[q] = *(const uint4*)(p0 + q * 32);
#pragma unroll
      for (int q = 0; q < 4; ++q) {
        ga[q * 8 + 0] += bflo(va[q].x);
        ga[q * 8 + 1] += bfhi(va[q].x);
        ga[q * 8 + 2] += bflo(va[q].y);
        ga[q * 8 + 3] += bfhi(va[q].y);
        ga[q * 8 + 4] += bflo(va[q].z);
        ga[q * 8 + 5] += bfhi(va[q].z);
        ga[q * 8 + 6] += bflo(va[q].w);
        ga[q * 8 + 7] += bfhi(va[q].w);
      }
    }
  }
  float iv = 1.0f / fmaxf((float)c, 1.0f);
  s16x8 am[4];  // mean in MFMA B-fragment form, quarters kk=0..3
#pragma unroll
  for (int q = 0; q < 4; ++q) {
    uint4 r;
    r.x = pack2(ga[q * 8 + 0] * iv, ga[q * 8 + 1] * iv);
    r.y = pack2(ga[q * 8 + 2] * iv, ga[q * 8 + 3] * iv);
    r.z = pack2(ga[q * 8 + 4] * iv, ga[q * 8 + 5] * iv);
    r.w = pack2(ga[q * 8 + 6] * iv, ga[q * 8 + 7] * iv);
    am[q] = __builtin_bit_cast(s16x8, r);
  }

  __syncthreads();  // W staged

  // ---- MFMA: 16 nodes x 128 outs, K=256 (mean regs | h global) ----
  f32x4 acc[8];
#pragma unroll
  for (int j = 0; j < 8; ++j) acc[j] = {0.f, 0.f, 0.f, 0.f};

#pragma unroll
  for (int kk = 0; kk < 8; ++kk) {
    s16x8 a;
    if (kk < 4) {
      a = am[kk];
    } else {
      a = *(const s16x8*)(h + (size_t)node * 128 + (kk - 4) * 32 + lq * 8);
    }
    const int ks = (kk * 4 + lq) ^ swz;
#pragma unroll
    for (int j = 0; j < 8; ++j) {
      int o = j * 16 + lr;
      s16x8 wf = *(const s16x8*)((const char*)Wlds + o * 512 + (ks << 4));
      acc[j] = __builtin_amdgcn_mfma_f32_16x16x32_bf16(wf, a, acc[j], 0, 0, 0);
    }
  }

  if (node < kN) {
#pragma unroll
    for (int j = 0; j < 8; ++j) {
      int o = j * 16 + lq * 4;
      float4 bv = *(const float4*)(bl + o);
      ushort4 r;
      r.x = bf16rne(fmaxf(acc[j][0] + bv.x, 0.f));
      r.y = bf16rne(fmaxf(acc[j][1] + bv.y, 0.f));
      r.z = bf16rne(fmaxf(acc[j][2] + bv.z, 0.f));
      r.w = bf16rne(fmaxf(acc[j][3] + bv.w, 0.f));
      *(ushort4*)(outp + (size_t)node * 128 + o) = r;
    }
  }
}

// ---------------- Pooling: 16 chunks per graph ----------------

__global__ __launch_bounds__(256) void pool_kernel(const ushort* __restrict__ h,
                                                   const int* __restrict__ gstart,
                                                   float* __restrict__ comb_raw,
                                                   int base) {
  __shared__ float part[4 * 128];
  int gb = blockIdx.x;
  int graph = gb >> 4;
  int chunk = gb & 15;
  int t = threadIdx.x;
  int slice = t >> 6;
  int col = t & 63;
  int s = gstart[graph];
  int e = gstart[graph + 1];
  int len = e - s;
  int c0 = s + (int)((long long)len * chunk / 16);
  int c1 = s + (int)((long long)len * (chunk + 1) / 16);
  float ax = 0.f, ay = 0.f;
  for (int n = c0 + slice; n < c1; n += 4) {
    uint v = *(const uint*)(h + (size_t)n * 128 + col * 2);
    ax += bflo(v);
    ay += bfhi(v);
  }
  part[slice * 128 + col * 2] = ax;
  part[slice * 128 + col * 2 + 1] = ay;
  __syncthreads();
  if (t < 128) {
    float v = part[t] + part[128 + t] + part[256 + t] + part[384 + t];
    atomicAdd(&comb_raw[graph * 256 + base + t], v);
  }
}

// ---------------- Heads ----------------

__global__ __launch_bounds__(256) void head_kernel(
    const float* __restrict__ comb_raw, const int* __restrict__ gstart,
    const float* __restrict__ gf,
    const float* __restrict__ neg, const float* __restrict__ neb,
    const float* __restrict__ fc1W, const float* __restrict__ fc1b,
    const float* __restrict__ bn1g, const float* __restrict__ bn1b,
    const float* __restrict__ fc2W, const float* __restrict__ fc2b,
    const float* __restrict__ fc3aW, const float* __restrict__ fc3ab,
    const float* __restrict__ fc3bW, const float* __restrict__ fc3bb,
    const float* __restrict__ ncg, const float* __restrict__ ncb,
    float* __restrict__ out) {
  __shared__ float wlds[6979];
  __shared__ float comb[256];
  __shared__ float x3[261];
  __shared__ float r2s[2];

  const int b = blockIdx.x;
  const int t = threadIdx.x;

  for (int i = t; i < 4112; i += 256) wlds[i] = fc1W[i];
  for (int i = t; i < 518; i += 256) wlds[4112 + i] = fc2W[i];
  for (int i = t; i < 1044; i += 256) wlds[4630 + i] = fc3aW[i];
  for (int i = t; i < 1305; i += 256) wlds[5674 + i] = fc3bW[i];

  float cntf = fmaxf((float)(gstart[b + 1] - gstart[b]), 1.0f);
  if (t < 256) comb[t] = neg[t] * ((comb_raw[b * 256 + t] / cntf) * kInvBN) + neb[t];
  __syncthreads();

  float g1 = gf[b * 5 + 1], g2 = gf[b * 5 + 2], g3 = gf[b * 5 + 3], g4 = gf[b * 5 + 4];
  const int g = t >> 3, l8 = t & 7;

  {
    float p = 0.f;
    if (g < 16) {
      const float* w = &wlds[g * 257];
      for (int j = l8; j < 256; j += 8) p += comb[j] * w[j];
    } else if (g < 18) {
      const float* w = &wlds[4112 + (g - 16) * 259];
      for (int j = l8; j < 256; j += 8) p += comb[j] * w[j];
    }
    p += __shfl_xor(p, 1);
    p += __shfl_xor(p, 2);
    p += __shfl_xor(p, 4);
    if (l8 == 0) {
      if (g < 16) {
        float z = fmaxf(p + wlds[g * 257 + 256] * g4 + fc1b[g], 0.f);
        out[b * 16 + g] = bn1g[g] * (z * kInvBN) + bn1b[g];
      } else if (g < 18) {
        int o = g - 16;
        const float* w = &wlds[4112 + o * 259];
        float z = fmaxf(p + w[256] * g2 + w[257] * g3 + w[258] * g4 + fc2b[o], 0.f);
        out[2048 + b * 2 + o] = z;
        r2s[o] = z;
      }
    }
  }
  for (int j = t; j < 261; j += 256) {
    float v;
    if (j < 256) v = comb[j];
    else if (j == 256) v = g2;
    else if (j == 257) v = g1;
    else if (j == 258) v = g2;
    else if (j == 259) v = g3;
    else v = g4;
    x3[j] = ncg[j] * (v * kInvBN) + ncb[j];
  }
  __syncthreads();
  int pred = (r2s[1] > r2s[0]) ? 1 : 0;

  {
    float p = 0.f;
    if (g < 4) {
      const float* w = &wlds[4630 + g * 261];
      for (int j = l8; j < 261; j += 8) p += x3[j] * w[j];
    } else if (g < 9) {
      const float* w = &wlds[5674 + (g - 4) * 261];
      for (int j = l8; j < 261; j += 8) p += x3[j] * w[j];
    }
    p += __shfl_xor(p, 1);
    p += __shfl_xor(p, 2);
    p += __shfl_xor(p, 4);
    if (l8 == 0) {
      if (g < 4) {
        float v = p + fc3ab[g];
        out[2304 + b * 9 + g] = (pred == 0) ? v : 0.f;
      } else if (g < 9) {
        int o = g - 4;
        float v = p + fc3bb[o];
        out[2304 + b * 9 + 4 + o] = (pred == 1) ? v : 0.f;
      }
    }
  }
}

// ---------------- Launch ----------------

extern "C" void kernel_launch(void* const* d_in, const int* in_sizes, int n_in,
                              void* d_out, int out_size, void* d_ws, size_t ws_size,
                              hipStream_t stream) {
  (void)in_sizes; (void)n_in; (void)out_size; (void)ws_size;
  const float* x   = (const float*)d_in[0];
  const int* ei    = (const int*)d_in[1];
  const int* ed    = (const int*)d_in[2];
  const int* batch = (const int*)d_in[3];
  const float* gf  = (const float*)d_in[4];

  char* ws = (char*)d_ws;
  auto carve = [&](size_t bytes) -> void* {
    void* p = ws;
    ws += (bytes + 255) & ~(size_t)255;
    return p;
  };
  int* cnt        = (int*)carve(2 * kN * sizeof(int));
  int* off        = (int*)carve(2 * kN * sizeof(int));
  int* cursor     = (int*)carve(2 * kN * sizeof(int));
  int* bsum       = (int*)carve(1024);
  int* gstart     = (int*)carve((kB + 1) * sizeof(int));
  int* csr        = (int*)carve(kE * sizeof(int));
  float* comb_raw = (float*)carve(kB * 256 * sizeof(float));
  ushort* xb      = (ushort*)carve((size_t)kNpad * 128 * 2);
  ushort* buf0    = (ushort*)carve((size_t)kNpad * 128 * 2);
  ushort* buf1    = (ushort*)carve((size_t)kNpad * 128 * 2);
  ushort* Wb      = (ushort*)carve(6 * 128 * 256 * 2);

  hipMemsetAsync(cnt, 0, 2 * kN * sizeof(int), stream);
  hipMemsetAsync(cursor, 0, 2 * kN * sizeof(int), stream);
  hipMemsetAsync(comb_raw, 0, kB * 256 * sizeof(float), stream);

  xconv_kernel<<<(kNpad * 128 / 4 + 255) / 256, 256, 0, stream>>>(x, xb);
  WPtrs wp;
  for (int L = 0; L < 6; ++L) {
    wp.Wl[L] = (const float*)d_in[6 + 3 * L];
    wp.Wr[L] = (const float*)d_in[6 + 3 * L + 2];
  }
  wprep_kernel<<<768, 256, 0, stream>>>(wp, Wb);

  count_kernel<<<(kE + 255) / 256, 256, 0, stream>>>(ei, ed, cnt);
  constexpr int M = 2 * kN;
  constexpr int NB = (M + 1023) / 1024;
  scan1_kernel<<<NB, 256, 0, stream>>>(cnt, off, bsum, M);
  scan2_kernel<<<1, 256, 0, stream>>>(bsum, NB);
  scan3_kernel<<<NB, 256, 0, stream>>>(off, bsum, M);
  fill_kernel<<<(kE + 255) / 256, 256, 0, stream>>>(ei, ed, off, cursor, csr);
  gstart_kernel<<<(kN + 255) / 256, 256, 0, stream>>>(batch, gstart);

  auto layerF = [&](const ushort* hin, ushort* hout, int L, int dirbase) {
    fused_layer_kernel<<<kNpad / 64, 256, 0, stream>>>(
        hin, hout, Wb + (size_t)L * 32768, (const float*)d_in[6 + 3 * L + 1],
        off, cnt, csr, dirbase);
  };

  // pre chain (dir bucket base 0)
  layerF(xb,   buf0, 0, 0);
  layerF(buf0, buf1, 1, 0);
  layerF(buf1, buf0, 2, 0);
  pool_kernel<<<kB * 16, 256, 0, stream>>>(buf0, gstart, comb_raw, 0);

  // suc chain (dir bucket base kN)
  layerF(xb,   buf1, 3, kN);
  layerF(buf1, buf0, 4, kN);
  layerF(buf0, buf1, 5, kN);
  pool_kernel<<<kB * 16, 256, 0, stream>>>(buf1, gstart, comb_raw, 128);

  head_kernel<<<kB, 256, 0, stream>>>(
      comb_raw, gstart, gf,
      (const float*)d_in[24], (const float*)d_in[25],
      (const float*)d_in[26], (const float*)d_in[27],
      (const float*)d_in[28], (const float*)d_in[29],
      (const float*)d_in[30], (const float*)d_in[31],
      (const float*)d_in[32], (const float*)d_in[33],
      (const float*)d_in[34], (const float*)d_in[35],
      (const float*)d_in[36], (const float*)d_in[37],
      (float*)d_out);
}

// Round 7
// 382.857 us; speedup vs baseline: 1.8834x; 1.0741x over previous
//
#include <hip/hip_runtime.h>

constexpr int kN = 100000;
constexpr int kNpad = 100096;      // 782 * 128
constexpr int kE = 800000;
constexpr int kB = 128;
constexpr int kBinsPerDir = 391;   // ceil(100000/256)
constexpr int kNB = 782;           // 2 * 391
constexpr int kRep = 16;
constexpr int kCtrs = kNB * kRep;  // 12512
constexpr float kInvBN = 0.99999500003749968f; // 1/sqrt(1+1e-5)

constexpr int kXconvBlocks = kNpad * 128 / 4 / 256;  // 12512
constexpr int kWprepBlocks = 768;
constexpr int kBincountBlocks = (kE + 255) / 256;    // 3125
constexpr int kGstartBlocks = (kN + 255) / 256;      // 391
constexpr int kPrepBlocks = kXconvBlocks + kWprepBlocks + kBincountBlocks + kGstartBlocks;

typedef short s16x8 __attribute__((ext_vector_type(8)));
typedef float f32x4 __attribute__((ext_vector_type(4)));

__device__ inline ushort bf16rne(float f) {
  uint u = __builtin_bit_cast(uint, f);
  u += 0x7fffu + ((u >> 16) & 1u);
  return (ushort)(u >> 16);
}
__device__ inline float bflo(uint v) { return __builtin_bit_cast(float, v << 16); }
__device__ inline float bfhi(uint v) { return __builtin_bit_cast(float, v & 0xffff0000u); }
__device__ inline uint pack2(float a, float b) {
  return (uint)bf16rne(a) | ((uint)bf16rne(b) << 16);
}

struct WPtrs { const float* Wl[6]; const float* Wr[6]; };

// ---------------- fused prep: xconv | wprep | bincount | gstart ----------------

__global__ __launch_bounds__(256) void prep_kernel(
    const float* __restrict__ x, ushort* __restrict__ xb,
    WPtrs p, ushort* __restrict__ Wb,
    const int* __restrict__ ei, const int* __restrict__ ed,
    int* __restrict__ bincnt,
    const int* __restrict__ batch, int* __restrict__ gstart) {
  int bi = blockIdx.x;
  int t = threadIdx.x;
  if (bi < kXconvBlocks) {
    int i4 = (bi * 256 + t) * 4;
    ushort4 r;
    if (i4 < kN * 128) {
      float4 v = *(const float4*)&x[i4];
      r.x = bf16rne(v.x); r.y = bf16rne(v.y); r.z = bf16rne(v.z); r.w = bf16rne(v.w);
    } else {
      r.x = r.y = r.z = r.w = 0;
    }
    *(ushort4*)&xb[i4] = r;
  } else if (bi < kXconvBlocks + kWprepBlocks) {
    int id = (bi - kXconvBlocks) * 256 + t;  // L*32768 + o*256 + k
    int L = id >> 15;
    int o = (id >> 8) & 127, k = id & 255;
    const float* src = (k < 128) ? p.Wl[L] : p.Wr[L];
    Wb[id] = bf16rne(src[o * 128 + (k & 127)]);
  } else if (bi < kXconvBlocks + kWprepBlocks + kBincountBlocks) {
    int e = (bi - kXconvBlocks - kWprepBlocks) * 256 + t;
    if (e < kE) {
      int dst = ei[kE + e];
      int ctr = (ed[e] * kBinsPerDir + (dst >> 8)) * kRep + ((e >> 8) & 15);
      atomicAdd(&bincnt[ctr], 1);
    }
  } else {
    int n = (bi - kXconvBlocks - kWprepBlocks - kBincountBlocks) * 256 + t;
    if (n < kN) {
      int b = batch[n];
      int bprev = (n == 0) ? -1 : batch[n - 1];
      for (int g = bprev + 1; g <= b; ++g) gstart[g] = n;
      if (n == kN - 1)
        for (int g = b + 1; g <= kB; ++g) gstart[g] = kN;
    }
  }
}

// ---------------- scans (generic) ----------------

__global__ __launch_bounds__(256) void scan1_kernel(const int* __restrict__ in,
                                                    int* __restrict__ out,
                                                    int* __restrict__ bsum, int M) {
  __shared__ int s[256];
  int t = threadIdx.x;
  int idx = blockIdx.x * 1024 + t * 4;
  int4 v = {0, 0, 0, 0};
  if (idx < M) v = *(const int4*)&in[idx];
  int tsum = v.x + v.y + v.z + v.w;
  s[t] = tsum;
  __syncthreads();
  for (int d = 1; d < 256; d <<= 1) {
    int tmp = (t >= d) ? s[t - d] : 0;
    __syncthreads();
    s[t] += tmp;
    __syncthreads();
  }
  int excl = s[t] - tsum;
  if (idx < M) {
    int4 o;
    o.x = excl; o.y = excl + v.x; o.z = o.y + v.y; o.w = o.z + v.z;
    *(int4*)&out[idx] = o;
  }
  if (t == 255) bsum[blockIdx.x] = s[255];
}

__global__ __launch_bounds__(256) void scan2_kernel(int* __restrict__ bsum, int nb) {
  __shared__ int s[256];
  int t = threadIdx.x;
  int v = (t < nb) ? bsum[t] : 0;
  s[t] = v;
  __syncthreads();
  for (int d = 1; d < 256; d <<= 1) {
    int tmp = (t >= d) ? s[t - d] : 0;
    __syncthreads();
    s[t] += tmp;
    __syncthreads();
  }
  if (t < nb) bsum[t] = s[t] - v;
}

__global__ __launch_bounds__(256) void scan3_kernel(int* __restrict__ out,
                                                    const int* __restrict__ bsum, int M) {
  int idx = blockIdx.x * 1024 + threadIdx.x * 4;
  int add = bsum[blockIdx.x];
  if (idx < M) {
    int4 o = *(int4*)&out[idx];
    o.x += add; o.y += add; o.z += add; o.w += add;
    *(int4*)&out[idx] = o;
  }
}

// ---------------- two-level sort: scatter + dense fill ----------------

__global__ __launch_bounds__(256) void binscatter_kernel(const int* __restrict__ ei,
                                                         const int* __restrict__ ed,
                                                         const int* __restrict__ binoff,
                                                         int* __restrict__ bincur,
                                                         uint* __restrict__ binbuf) {
  int e = blockIdx.x * 256 + threadIdx.x;
  if (e >= kE) return;
  int dst = ei[kE + e];
  int ctr = (ed[e] * kBinsPerDir + (dst >> 8)) * kRep + ((e >> 8) & 15);
  int pos = atomicAdd(&bincur[ctr], 1);
  binbuf[binoff[ctr] + pos] = (uint)ei[e] | ((uint)(dst & 255) << 17);
}

// one block per bin: local degree count + scan, dense csr/cnt/off writes
__global__ __launch_bounds__(256) void binfill_kernel(const uint* __restrict__ binbuf,
                                                      const int* __restrict__ binoff,
                                                      int* __restrict__ csr,
                                                      int* __restrict__ cnt,
                                                      int* __restrict__ off) {
  __shared__ int lcnt[256];
  __shared__ int ls[256];
  __shared__ int lpos[256];
  int b = blockIdx.x;
  int t = threadIdx.x;
  int dir = (b >= kBinsPerDir) ? 1 : 0;
  int nodeBase = (b - dir * kBinsPerDir) << 8;
  int e0 = binoff[b * kRep];
  int e1 = (b == kNB - 1) ? kE : binoff[(b + 1) * kRep];
  lcnt[t] = 0;
  __syncthreads();
  for (int e = e0 + t; e < e1; e += 256) atomicAdd(&lcnt[binbuf[e] >> 17], 1);
  __syncthreads();
  int my = lcnt[t];
  ls[t] = my;
  __syncthreads();
  for (int d = 1; d < 256; d <<= 1) {
    int tmp = (t >= d) ? ls[t - d] : 0;
    __syncthreads();
    ls[t] += tmp;
    __syncthreads();
  }
  int excl = ls[t] - my;
  lpos[t] = e0 + excl;
  int node = nodeBase + t;
  if (node < kN) {
    int g = dir * kN + node;
    cnt[g] = my;
    off[g] = e0 + excl;
  }
  __syncthreads();
  for (int e = e0 + t; e < e1; e += 256) {
    uint v = binbuf[e];
    int pos = atomicAdd(&lpos[v >> 17], 1);
    csr[pos] = (int)(v & 0x1FFFFu);
  }
}

// ---------------- Fused SAGE layer: gather-mean in registers + MFMA ----------------
// 512 threads = 8 waves share one 64KB W stage -> 16 waves/CU residency.

__global__ __launch_bounds__(512) void fused_layer_kernel(
    const ushort* __restrict__ h,      // [kNpad][128] bf16 input features
    ushort* __restrict__ outp,         // [kNpad][128] bf16 output
    const ushort* __restrict__ Wb,     // [128][256] bf16
    const float* __restrict__ bl,
    const int* __restrict__ off,
    const int* __restrict__ cnt,
    const int* __restrict__ csr,
    int dirbase) {
  __shared__ ushort Wlds[128 * 256];   // 64 KB, 16B-block XOR swizzled

  const int t = threadIdx.x;
#pragma unroll
  for (int it = 0; it < 8; ++it) {
    int u = t + 512 * it;
    int o = u >> 5, b = u & 31;
    uint4 v = *(const uint4*)(Wb + (size_t)u * 8);
    *(uint4*)((char*)Wlds + o * 512 + ((b ^ (o & 7)) << 4)) = v;
  }

  const int w = t >> 6;
  const int l = t & 63;
  const int lr = l & 15;
  const int lq = l >> 4;
  const int node = blockIdx.x * 128 + w * 16 + lr;
  const int swz = lr & 7;

  // ---- gather + mean (registers only) ----
  float ga[32];
#pragma unroll
  for (int i = 0; i < 32; ++i) ga[i] = 0.f;
  int c = 0;
  if (node < kN) {
    int bkt = dirbase + node;
    int s = off[bkt];
    c = cnt[bkt];
    const ushort* hp = h + lq * 8;
    int e = 0;
    for (; e + 2 <= c; e += 2) {
      int s0 = csr[s + e];
      int s1 = csr[s + e + 1];
      const ushort* p0 = hp + (size_t)s0 * 128;
      const ushort* p1 = hp + (size_t)s1 * 128;
      uint4 va[4], vb[4];
#pragma unroll
      for (int q = 0; q < 4; ++q) va[q] = *(const uint4*)(p0 + q * 32);
#pragma unroll
      for (int q = 0; q < 4; ++q) vb[q] = *(const uint4*)(p1 + q * 32);
#pragma unroll
      for (int q = 0; q < 4; ++q) {
        ga[q * 8 + 0] += bflo(va[q].x) + bflo(vb[q].x);
        ga[q * 8 + 1] += bfhi(va[q].x) + bfhi(vb[q].x);
        ga[q * 8 + 2] += bflo(va[q].y) + bflo(vb[q].y);
        ga[q * 8 + 3] += bfhi(va[q].y) + bfhi(vb[q].y);
        ga[q * 8 + 4] += bflo(va[q].z) + bflo(vb[q].z);
        ga[q * 8 + 5] += bfhi(va[q].z) + bfhi(vb[q].z);
        ga[q * 8 + 6] += bflo(va[q].w) + bflo(vb[q].w);
        ga[q * 8 + 7] += bfhi(va[q].w) + bfhi(vb[q].w);
      }
    }
    if (e < c) {
      int s0 = csr[s + e];
      const ushort* p0 = hp + (size_t)s0 * 128;
      uint4 va[4];
#pragma unroll
      for (int q = 0; q < 4; ++q) va[q] = *(const uint4*)(p0 + q * 32);
#pragma unroll
      for (int q = 0; q < 4; ++q) {
        ga[q * 8 + 0] += bflo(va[q].x);
        ga[q * 8 + 1] += bfhi(va[q].x);
        ga[q * 8 + 2] += bflo(va[q].y);
        ga[q * 8 + 3] += bfhi(va[q].y);
        ga[q * 8 + 4] += bflo(va[q].z);
        ga[q * 8 + 5] += bfhi(va[q].z);
        ga[q * 8 + 6] += bflo(va[q].w);
        ga[q * 8 + 7] += bfhi(va[q].w);
      }
    }
  }
  float iv = 1.0f / fmaxf((float)c, 1.0f);
  s16x8 am[4];  // mean in MFMA B-fragment form, quarters kk=0..3
#pragma unroll
  for (int q = 0; q < 4; ++q) {
    uint4 r;
    r.x = pack2(ga[q * 8 + 0] * iv, ga[q * 8 + 1] * iv);
    r.y = pack2(ga[q * 8 + 2] * iv, ga[q * 8 + 3] * iv);
    r.z = pack2(ga[q * 8 + 4] * iv, ga[q * 8 + 5] * iv);
    r.w = pack2(ga[q * 8 + 6] * iv, ga[q * 8 + 7] * iv);
    am[q] = __builtin_bit_cast(s16x8, r);
  }

  __syncthreads();  // W staged

  // ---- MFMA: 16 nodes x 128 outs, K=256 (mean regs | h global) ----
  f32x4 acc[8];
#pragma unroll
  for (int j = 0; j < 8; ++j) acc[j] = {0.f, 0.f, 0.f, 0.f};

#pragma unroll
  for (int kk = 0; kk < 8; ++kk) {
    s16x8 a;
    if (kk < 4) {
      a = am[kk];
    } else {
      a = *(const s16x8*)(h + (size_t)node * 128 + (kk - 4) * 32 + lq * 8);
    }
    const int ks = (kk * 4 + lq) ^ swz;
#pragma unroll
    for (int j = 0; j < 8; ++j) {
      int o = j * 16 + lr;
      s16x8 wf = *(const s16x8*)((const char*)Wlds + o * 512 + (ks << 4));
      acc[j] = __builtin_amdgcn_mfma_f32_16x16x32_bf16(wf, a, acc[j], 0, 0, 0);
    }
  }

  if (node < kN) {
#pragma unroll
    for (int j = 0; j < 8; ++j) {
      int o = j * 16 + lq * 4;
      float4 bv = *(const float4*)(bl + o);
      ushort4 r;
      r.x = bf16rne(fmaxf(acc[j][0] + bv.x, 0.f));
      r.y = bf16rne(fmaxf(acc[j][1] + bv.y, 0.f));
      r.z = bf16rne(fmaxf(acc[j][2] + bv.z, 0.f));
      r.w = bf16rne(fmaxf(acc[j][3] + bv.w, 0.f));
      *(ushort4*)(outp + (size_t)node * 128 + o) = r;
    }
  }
}

// ---------------- Pooling: 16 chunks per graph ----------------

__global__ __launch_bounds__(256) void pool_kernel(const ushort* __restrict__ h,
                                                   const int* __restrict__ gstart,
                                                   float* __restrict__ comb_raw,
                                                   int base) {
  __shared__ float part[4 * 128];
  int gb = blockIdx.x;
  int graph = gb >> 4;
  int chunk = gb & 15;
  int t = threadIdx.x;
  int slice = t >> 6;
  int col = t & 63;
  int s = gstart[graph];
  int e = gstart[graph + 1];
  int len = e - s;
  int c0 = s + (int)((long long)len * chunk / 16);
  int c1 = s + (int)((long long)len * (chunk + 1) / 16);
  float ax = 0.f, ay = 0.f;
  for (int n = c0 + slice; n < c1; n += 4) {
    uint v = *(const uint*)(h + (size_t)n * 128 + col * 2);
    ax += bflo(v);
    ay += bfhi(v);
  }
  part[slice * 128 + col * 2] = ax;
  part[slice * 128 + col * 2 + 1] = ay;
  __syncthreads();
  if (t < 128) {
    float v = part[t] + part[128 + t] + part[256 + t] + part[384 + t];
    atomicAdd(&comb_raw[graph * 256 + base + t], v);
  }
}

// ---------------- Heads ----------------

__global__ __launch_bounds__(256) void head_kernel(
    const float* __restrict__ comb_raw, const int* __restrict__ gstart,
    const float* __restrict__ gf,
    const float* __restrict__ neg, const float* __restrict__ neb,
    const float* __restrict__ fc1W, const float* __restrict__ fc1b,
    const float* __restrict__ bn1g, const float* __restrict__ bn1b,
    const float* __restrict__ fc2W, const float* __restrict__ fc2b,
    const float* __restrict__ fc3aW, const float* __restrict__ fc3ab,
    const float* __restrict__ fc3bW, const float* __restrict__ fc3bb,
    const float* __restrict__ ncg, const float* __restrict__ ncb,
    float* __restrict__ out) {
  __shared__ float wlds[6979];
  __shared__ float comb[256];
  __shared__ float x3[261];
  __shared__ float r2s[2];

  const int b = blockIdx.x;
  const int t = threadIdx.x;

  for (int i = t; i < 4112; i += 256) wlds[i] = fc1W[i];
  for (int i = t; i < 518; i += 256) wlds[4112 + i] = fc2W[i];
  for (int i = t; i < 1044; i += 256) wlds[4630 + i] = fc3aW[i];
  for (int i = t; i < 1305; i += 256) wlds[5674 + i] = fc3bW[i];

  float cntf = fmaxf((float)(gstart[b + 1] - gstart[b]), 1.0f);
  if (t < 256) comb[t] = neg[t] * ((comb_raw[b * 256 + t] / cntf) * kInvBN) + neb[t];
  __syncthreads();

  float g1 = gf[b * 5 + 1], g2 = gf[b * 5 + 2], g3 = gf[b * 5 + 3], g4 = gf[b * 5 + 4];
  const int g = t >> 3, l8 = t & 7;

  {
    float p = 0.f;
    if (g < 16) {
      const float* w = &wlds[g * 257];
      for (int j = l8; j < 256; j += 8) p += comb[j] * w[j];
    } else if (g < 18) {
      const float* w = &wlds[4112 + (g - 16) * 259];
      for (int j = l8; j < 256; j += 8) p += comb[j] * w[j];
    }
    p += __shfl_xor(p, 1);
    p += __shfl_xor(p, 2);
    p += __shfl_xor(p, 4);
    if (l8 == 0) {
      if (g < 16) {
        float z = fmaxf(p + wlds[g * 257 + 256] * g4 + fc1b[g], 0.f);
        out[b * 16 + g] = bn1g[g] * (z * kInvBN) + bn1b[g];
      } else if (g < 18) {
        int o = g - 16;
        const float* w = &wlds[4112 + o * 259];
        float z = fmaxf(p + w[256] * g2 + w[257] * g3 + w[258] * g4 + fc2b[o], 0.f);
        out[2048 + b * 2 + o] = z;
        r2s[o] = z;
      }
    }
  }
  for (int j = t; j < 261; j += 256) {
    float v;
    if (j < 256) v = comb[j];
    else if (j == 256) v = g2;
    else if (j == 257) v = g1;
    else if (j == 258) v = g2;
    else if (j == 259) v = g3;
    else v = g4;
    x3[j] = ncg[j] * (v * kInvBN) + ncb[j];
  }
  __syncthreads();
  int pred = (r2s[1] > r2s[0]) ? 1 : 0;

  {
    float p = 0.f;
    if (g < 4) {
      const float* w = &wlds[4630 + g * 261];
      for (int j = l8; j < 261; j += 8) p += x3[j] * w[j];
    } else if (g < 9) {
      const float* w = &wlds[5674 + (g - 4) * 261];
      for (int j = l8; j < 261; j += 8) p += x3[j] * w[j];
    }
    p += __shfl_xor(p, 1);
    p += __shfl_xor(p, 2);
    p += __shfl_xor(p, 4);
    if (l8 == 0) {
      if (g < 4) {
        float v = p + fc3ab[g];
        out[2304 + b * 9 + g] = (pred == 0) ? v : 0.f;
      } else if (g < 9) {
        int o = g - 4;
        float v = p + fc3bb[o];
        out[2304 + b * 9 + 4 + o] = (pred == 1) ? v : 0.f;
      }
    }
  }
}

// ---------------- Launch ----------------

extern "C" void kernel_launch(void* const* d_in, const int* in_sizes, int n_in,
                              void* d_out, int out_size, void* d_ws, size_t ws_size,
                              hipStream_t stream) {
  (void)in_sizes; (void)n_in; (void)out_size; (void)ws_size;
  const float* x   = (const float*)d_in[0];
  const int* ei    = (const int*)d_in[1];
  const int* ed    = (const int*)d_in[2];
  const int* batch = (const int*)d_in[3];
  const float* gf  = (const float*)d_in[4];

  char* ws = (char*)d_ws;
  auto carve = [&](size_t bytes) -> void* {
    void* p = ws;
    ws += (bytes + 255) & ~(size_t)255;
    return p;
  };
  int* cnt        = (int*)carve(2 * kN * sizeof(int));
  int* off        = (int*)carve(2 * kN * sizeof(int));
  int* bincnt     = (int*)carve(kCtrs * sizeof(int));
  int* bincur     = (int*)carve(kCtrs * sizeof(int));
  int* binoff     = (int*)carve((kCtrs + 4) * sizeof(int));
  int* bsum       = (int*)carve(1024);
  int* gstart     = (int*)carve((kB + 1) * sizeof(int));
  int* csr        = (int*)carve(kE * sizeof(int));
  uint* binbuf    = (uint*)carve(kE * sizeof(uint));
  float* comb_raw = (float*)carve(kB * 256 * sizeof(float));
  ushort* xb      = (ushort*)carve((size_t)kNpad * 128 * 2);
  ushort* buf0    = (ushort*)carve((size_t)kNpad * 128 * 2);
  ushort* buf1    = (ushort*)carve((size_t)kNpad * 128 * 2);
  ushort* Wb      = (ushort*)carve(6 * 128 * 256 * 2);

  hipMemsetAsync(bincnt, 0, kCtrs * sizeof(int), stream);
  hipMemsetAsync(bincur, 0, kCtrs * sizeof(int), stream);
  hipMemsetAsync(comb_raw, 0, kB * 256 * sizeof(float), stream);

  WPtrs wp;
  for (int L = 0; L < 6; ++L) {
    wp.Wl[L] = (const float*)d_in[6 + 3 * L];
    wp.Wr[L] = (const float*)d_in[6 + 3 * L + 2];
  }

  prep_kernel<<<kPrepBlocks, 256, 0, stream>>>(x, xb, wp, Wb, ei, ed, bincnt, batch, gstart);

  constexpr int NBScan = (kCtrs + 1023) / 1024;  // 13
  scan1_kernel<<<NBScan, 256, 0, stream>>>(bincnt, binoff, bsum, kCtrs);
  scan2_kernel<<<1, 256, 0, stream>>>(bsum, NBScan);
  scan3_kernel<<<NBScan, 256, 0, stream>>>(binoff, bsum, kCtrs);
  binscatter_kernel<<<(kE + 255) / 256, 256, 0, stream>>>(ei, ed, binoff, bincur, binbuf);
  binfill_kernel<<<kNB, 256, 0, stream>>>(binbuf, binoff, csr, cnt, off);

  auto layerF = [&](const ushort* hin, ushort* hout, int L, int dirbase) {
    fused_layer_kernel<<<kNpad / 128, 512, 0, stream>>>(
        hin, hout, Wb + (size_t)L * 32768, (const float*)d_in[6 + 3 * L + 1],
        off, cnt, csr, dirbase);
  };

  // pre chain (dir bucket base 0)
  layerF(xb,   buf0, 0, 0);
  layerF(buf0, buf1, 1, 0);
  layerF(buf1, buf0, 2, 0);
  pool_kernel<<<kB * 16, 256, 0, stream>>>(buf0, gstart, comb_raw, 0);

  // suc chain (dir bucket base kN)
  layerF(xb,   buf1, 3, kN);
  layerF(buf1, buf0, 4, kN);
  layerF(buf0, buf1, 5, kN);
  pool_kernel<<<kB * 16, 256, 0, stream>>>(buf1, gstart, comb_raw, 128);

  head_kernel<<<kB, 256, 0, stream>>>(
      comb_raw, gstart, gf,
      (const float*)d_in[24], (const float*)d_in[25],
      (const float*)d_in[26], (const float*)d_in[27],
      (const float*)d_in[28], (const float*)d_in[29],
      (const float*)d_in[30], (const float*)d_in[31],
      (const float*)d_in[32], (const float*)d_in[33],
      (const float*)d_in[34], (const float*)d_in[35],
      (const float*)d_in[36], (const float*)d_in[37],
      (float*)d_out);
}